// Round 1
// baseline (45.304 us; speedup 1.0000x reference)
//
#include <hip/hip_runtime.h>

// Jacobi damped smoother: out = x + (w/k[1][1]) * (f - conv3x3(x, k)), zero padding.
// B=64, H=512, W=512, fp32. Memory-bound: min traffic 192 MB.

__global__ __launch_bounds__(256) void jacobi_kernel(
    const float* __restrict__ x,
    const float* __restrict__ f,
    const float* __restrict__ kA,
    float* __restrict__ out)
{
    // t = b*65536 + i*128 + g ; each thread computes 4 pixels (one float4)
    const int t  = blockIdx.x * blockDim.x + threadIdx.x;
    const int g  = t & 127;          // float4-group within row
    const int i  = (t >> 7) & 511;   // row
    const int b  = t >> 16;          // batch
    const int j0 = g << 2;           // starting column

    // Per-batch 3x3 kernel (b is uniform across the block -> broadcast loads)
    const float* kb = kA + b * 9;
    const float k00 = kb[0], k01 = kb[1], k02 = kb[2];
    const float k10 = kb[3], k11 = kb[4], k12 = kb[5];
    const float k20 = kb[6], k21 = kb[7], k22 = kb[8];
    const float weight = (2.0f / 3.0f) / k11;

    const size_t plane = (size_t)b << 18;   // 512*512
    const size_t rowoff = (size_t)i << 9;   // i*512

    const float* xb = x + plane;

    float r0[6], r1[6], r2[6];

    // middle row (always valid)
    {
        const float* p = xb + rowoff;
        const float4 c = *(const float4*)(p + j0);
        r1[1] = c.x; r1[2] = c.y; r1[3] = c.z; r1[4] = c.w;
        r1[0] = (j0 > 0)   ? p[j0 - 1] : 0.0f;
        r1[5] = (j0 < 508) ? p[j0 + 4] : 0.0f;
    }
    // top row
    if (i > 0) {
        const float* p = xb + rowoff - 512;
        const float4 c = *(const float4*)(p + j0);
        r0[1] = c.x; r0[2] = c.y; r0[3] = c.z; r0[4] = c.w;
        r0[0] = (j0 > 0)   ? p[j0 - 1] : 0.0f;
        r0[5] = (j0 < 508) ? p[j0 + 4] : 0.0f;
    } else {
        r0[0] = r0[1] = r0[2] = r0[3] = r0[4] = r0[5] = 0.0f;
    }
    // bottom row
    if (i < 511) {
        const float* p = xb + rowoff + 512;
        const float4 c = *(const float4*)(p + j0);
        r2[1] = c.x; r2[2] = c.y; r2[3] = c.z; r2[4] = c.w;
        r2[0] = (j0 > 0)   ? p[j0 - 1] : 0.0f;
        r2[5] = (j0 < 508) ? p[j0 + 4] : 0.0f;
    } else {
        r2[0] = r2[1] = r2[2] = r2[3] = r2[4] = r2[5] = 0.0f;
    }

    const float4 fv = *(const float4*)(f + plane + rowoff + j0);
    const float fx[4] = { fv.x, fv.y, fv.z, fv.w };

    float res[4];
    #pragma unroll
    for (int p = 0; p < 4; ++p) {
        float Ax = k00 * r0[p] + k01 * r0[p + 1] + k02 * r0[p + 2]
                 + k10 * r1[p] + k11 * r1[p + 1] + k12 * r1[p + 2]
                 + k20 * r2[p] + k21 * r2[p + 1] + k22 * r2[p + 2];
        res[p] = r1[p + 1] + weight * (fx[p] - Ax);
    }

    *(float4*)(out + plane + rowoff + j0) = make_float4(res[0], res[1], res[2], res[3]);
}

extern "C" void kernel_launch(void* const* d_in, const int* in_sizes, int n_in,
                              void* d_out, int out_size, void* d_ws, size_t ws_size,
                              hipStream_t stream) {
    const float* x  = (const float*)d_in[0];
    const float* f  = (const float*)d_in[1];
    const float* kA = (const float*)d_in[2];
    float* out = (float*)d_out;

    // total threads = 64 * 512 * 128 = 4194304 ; block 256 -> 16384 blocks
    const int total = 64 * 512 * 128;
    const int block = 256;
    const int grid  = total / block;
    jacobi_kernel<<<grid, block, 0, stream>>>(x, f, kA, out);
}

// Round 3
// 42.364 us; speedup vs baseline: 1.0694x; 1.0694x over previous
//
#include <hip/hip_runtime.h>

// Jacobi damped smoother: out = x + (w/k11) * (f - conv3x3(x, k)), zero padding.
// B=64, H=512, W=512, fp32.
// One wave covers a full 512-col row (8 cols/lane); halos via shfl, not memory.
// Each wave processes ROWS=4 consecutive rows -> x rows loaded (ROWS+2)/ROWS = 1.5x.
// Nontemporal stores keep out from evicting x+f (128 MB) out of the 256 MB L3.

#define ROWS 4

typedef float f32x4 __attribute__((ext_vector_type(4)));

__global__ __launch_bounds__(256) void jacobi_kernel(
    const float* __restrict__ x,
    const float* __restrict__ f,
    const float* __restrict__ kA,
    float* __restrict__ out)
{
    const int tid  = blockIdx.x * blockDim.x + threadIdx.x;
    const int lane = tid & 63;
    const int wid  = tid >> 6;
    const int strip = wid & 127;        // 512 / ROWS = 128 strips per batch
    const int b     = wid >> 7;
    const int r0    = strip * ROWS;
    const int c0    = lane << 3;        // 8 columns per lane

    // per-batch 3x3 kernel (uniform across the wave -> scalar broadcast)
    const float* kb = kA + b * 9;
    const float k00 = kb[0], k01 = kb[1], k02 = kb[2];
    const float k10 = kb[3], k11 = kb[4], k12 = kb[5];
    const float k20 = kb[6], k21 = kb[7], k22 = kb[8];
    const float weight = (2.0f / 3.0f) / k11;

    const size_t plane = (size_t)b << 18;       // 512*512
    const float* xb = x + plane;
    const float* fb = f + plane + ((size_t)r0 << 9) + c0;
    float*       ob = out + plane + ((size_t)r0 << 9) + c0;

    // ---- load ROWS+2 x-rows, 8 wide + 2 halo slots each (all static indexing) ----
    float xr[ROWS + 2][10];
    #pragma unroll
    for (int q = 0; q < ROWS + 2; ++q) {
        const int r = r0 - 1 + q;               // wave-uniform validity
        if (r >= 0 && r < 512) {
            const float* p = xb + ((size_t)r << 9) + c0;
            const f32x4 a = *(const f32x4*)p;
            const f32x4 c = *(const f32x4*)(p + 4);
            xr[q][1] = a.x; xr[q][2] = a.y; xr[q][3] = a.z; xr[q][4] = a.w;
            xr[q][5] = c.x; xr[q][6] = c.y; xr[q][7] = c.z; xr[q][8] = c.w;
        } else {
            #pragma unroll
            for (int c2 = 1; c2 < 9; ++c2) xr[q][c2] = 0.0f;
        }
    }

    // ---- halos via cross-lane shuffle (wave spans the full row) ----
    #pragma unroll
    for (int q = 0; q < ROWS + 2; ++q) {
        float left  = __shfl_up(xr[q][8], 1);
        float right = __shfl_down(xr[q][1], 1);
        xr[q][0] = (lane == 0)  ? 0.0f : left;   // image left edge -> 0
        xr[q][9] = (lane == 63) ? 0.0f : right;  // image right edge -> 0
    }

    // ---- per output row: load f, stencil, nontemporal store ----
    #pragma unroll
    for (int rr = 0; rr < ROWS; ++rr) {
        const float* fp = fb + ((size_t)rr << 9);
        const f32x4 f0 = *(const f32x4*)fp;
        const f32x4 f1 = *(const f32x4*)(fp + 4);
        const float fx[8] = { f0.x, f0.y, f0.z, f0.w, f1.x, f1.y, f1.z, f1.w };

        float res[8];
        #pragma unroll
        for (int p = 0; p < 8; ++p) {
            float Ax = k00 * xr[rr][p]     + k01 * xr[rr][p + 1]     + k02 * xr[rr][p + 2]
                     + k10 * xr[rr + 1][p] + k11 * xr[rr + 1][p + 1] + k12 * xr[rr + 1][p + 2]
                     + k20 * xr[rr + 2][p] + k21 * xr[rr + 2][p + 1] + k22 * xr[rr + 2][p + 2];
            res[p] = xr[rr + 1][p + 1] + weight * (fx[p] - Ax);
        }

        float* op = ob + ((size_t)rr << 9);
        f32x4 v0 = { res[0], res[1], res[2], res[3] };
        f32x4 v1 = { res[4], res[5], res[6], res[7] };
        __builtin_nontemporal_store(v0, (f32x4*)op);
        __builtin_nontemporal_store(v1, (f32x4*)(op + 4));
    }
}

extern "C" void kernel_launch(void* const* d_in, const int* in_sizes, int n_in,
                              void* d_out, int out_size, void* d_ws, size_t ws_size,
                              hipStream_t stream) {
    const float* x  = (const float*)d_in[0];
    const float* f  = (const float*)d_in[1];
    const float* kA = (const float*)d_in[2];
    float* out = (float*)d_out;

    // waves = 64 batches * 128 strips = 8192 ; threads = 524288 ; blocks = 2048
    const int total = 64 * (512 / ROWS) * 64;
    const int block = 256;
    const int grid  = total / block;
    jacobi_kernel<<<grid, block, 0, stream>>>(x, f, kA, out);
}

// Round 4
// 36.683 us; speedup vs baseline: 1.2350x; 1.1549x over previous
//
#include <hip/hip_runtime.h>

// Jacobi damped smoother: out = x + (w/k11) * (f - conv3x3(x, k)), zero padding.
// B=64, H=512, W=512, fp32.
// One wave covers a full 512-col row (8 cols/lane); halos via shfl, not memory.
// ROWS=2 rows per wave -> 16384 waves (4096 blocks): latency hiding over reuse.
// Normal cached stores: x+f+out = 192 MB fits the 256 MB Infinity Cache.

#define ROWS 2

typedef float f32x4 __attribute__((ext_vector_type(4)));

__global__ __launch_bounds__(256) void jacobi_kernel(
    const float* __restrict__ x,
    const float* __restrict__ f,
    const float* __restrict__ kA,
    float* __restrict__ out)
{
    const int tid  = blockIdx.x * blockDim.x + threadIdx.x;
    const int lane = tid & 63;
    const int wid  = tid >> 6;
    const int strip = wid & 255;        // 512 / ROWS = 256 strips per batch
    const int b     = wid >> 8;
    const int r0    = strip * ROWS;
    const int c0    = lane << 3;        // 8 columns per lane

    // per-batch 3x3 kernel (uniform across the wave -> scalar broadcast)
    const float* kb = kA + b * 9;
    const float k00 = kb[0], k01 = kb[1], k02 = kb[2];
    const float k10 = kb[3], k11 = kb[4], k12 = kb[5];
    const float k20 = kb[6], k21 = kb[7], k22 = kb[8];
    const float weight = (2.0f / 3.0f) / k11;

    const size_t plane = (size_t)b << 18;       // 512*512
    const float* xb = x + plane;
    const float* fb = f + plane + ((size_t)r0 << 9) + c0;
    float*       ob = out + plane + ((size_t)r0 << 9) + c0;

    // ---- load ROWS+2 x-rows, 8 wide + 2 halo slots each (all static indexing) ----
    float xr[ROWS + 2][10];
    #pragma unroll
    for (int q = 0; q < ROWS + 2; ++q) {
        const int r = r0 - 1 + q;               // wave-uniform validity
        if (r >= 0 && r < 512) {
            const float* p = xb + ((size_t)r << 9) + c0;
            const f32x4 a = *(const f32x4*)p;
            const f32x4 c = *(const f32x4*)(p + 4);
            xr[q][1] = a.x; xr[q][2] = a.y; xr[q][3] = a.z; xr[q][4] = a.w;
            xr[q][5] = c.x; xr[q][6] = c.y; xr[q][7] = c.z; xr[q][8] = c.w;
        } else {
            #pragma unroll
            for (int c2 = 1; c2 < 9; ++c2) xr[q][c2] = 0.0f;
        }
    }

    // ---- halos via cross-lane shuffle (wave spans the full row) ----
    #pragma unroll
    for (int q = 0; q < ROWS + 2; ++q) {
        float left  = __shfl_up(xr[q][8], 1);
        float right = __shfl_down(xr[q][1], 1);
        xr[q][0] = (lane == 0)  ? 0.0f : left;   // image left edge -> 0
        xr[q][9] = (lane == 63) ? 0.0f : right;  // image right edge -> 0
    }

    // ---- per output row: load f, stencil, store ----
    #pragma unroll
    for (int rr = 0; rr < ROWS; ++rr) {
        const float* fp = fb + ((size_t)rr << 9);
        const f32x4 f0 = *(const f32x4*)fp;
        const f32x4 f1 = *(const f32x4*)(fp + 4);
        const float fx[8] = { f0.x, f0.y, f0.z, f0.w, f1.x, f1.y, f1.z, f1.w };

        float res[8];
        #pragma unroll
        for (int p = 0; p < 8; ++p) {
            float Ax = k00 * xr[rr][p]     + k01 * xr[rr][p + 1]     + k02 * xr[rr][p + 2]
                     + k10 * xr[rr + 1][p] + k11 * xr[rr + 1][p + 1] + k12 * xr[rr + 1][p + 2]
                     + k20 * xr[rr + 2][p] + k21 * xr[rr + 2][p + 1] + k22 * xr[rr + 2][p + 2];
            res[p] = xr[rr + 1][p + 1] + weight * (fx[p] - Ax);
        }

        float* op = ob + ((size_t)rr << 9);
        f32x4 v0 = { res[0], res[1], res[2], res[3] };
        f32x4 v1 = { res[4], res[5], res[6], res[7] };
        *(f32x4*)op       = v0;
        *(f32x4*)(op + 4) = v1;
    }
}

extern "C" void kernel_launch(void* const* d_in, const int* in_sizes, int n_in,
                              void* d_out, int out_size, void* d_ws, size_t ws_size,
                              hipStream_t stream) {
    const float* x  = (const float*)d_in[0];
    const float* f  = (const float*)d_in[1];
    const float* kA = (const float*)d_in[2];
    float* out = (float*)d_out;

    // waves = 64 batches * 256 strips = 16384 ; threads = 1048576 ; blocks = 4096
    const int total = 64 * (512 / ROWS) * 64;
    const int block = 256;
    const int grid  = total / block;
    jacobi_kernel<<<grid, block, 0, stream>>>(x, f, kA, out);
}